// Round 14
// baseline (214.796 us; speedup 1.0000x reference)
//
#include <hip/hip_runtime.h>
#include <hip/hip_bf16.h>
#include <math.h>

// ---------------------------------------------------------------------------
// Expansion kernel.  Q-form fusion: out[b,uv] = sum_k Q[b,k]*LW2T[n(uv),k]
// Round 14: round-13 source with ONE change: __launch_bounds__(1024, 2).
// Round 13 (1024 threads, launch_bounds(1024,1)) let the allocator pick
// VGPR=64 -> scratch spill (WRITE 270MB = 103 out + 167 spill, FETCH 95MB)
// yet still only -28% -- TLP absorbed most of the spill cost, so 16 waves
// at the full 128-VGPR budget should win.  Empirical launch-bounds law
// (rounds 1-13): cap = 512/(2*arg2): (256,2)->128, (256,3)->84,
// (512,4)->64.  So (1024,2) -> 128 VGPR, no spill (round 9/10 codegen fit
// 128 with LARGER helpers; round 13's halved-N helpers need less).
// Everything else byte-identical to round 13 (passing).
// ---------------------------------------------------------------------------

typedef short bf16x8 __attribute__((ext_vector_type(8)));
typedef float f32x4 __attribute__((ext_vector_type(4)));

static __device__ __forceinline__ short f2bf(float f) {
  unsigned u = __builtin_bit_cast(unsigned, f);
  u = u + 0x7fffu + ((u >> 16) & 1u);   // round-to-nearest-even
  return (short)(u >> 16);
}

// ---- pre-pass 1: LW2 [64][36864] f32 -> LW2T bf16 [36864][64] ------------
__global__ void k_transpose(const float* __restrict__ lw2, short* __restrict__ lw2t) {
  __shared__ float tile[64][65];
  int n0 = blockIdx.x * 64;
  int t = threadIdx.x;
#pragma unroll
  for (int k = 0; k < 16; ++k) {
    int idx = k * 256 + t;
    int c = idx >> 6, j = idx & 63;
    tile[c][j] = lw2[(size_t)c * 36864 + n0 + j];
  }
  __syncthreads();
#pragma unroll
  for (int k = 0; k < 16; ++k) {
    int idx = k * 256 + t;
    int n = idx >> 6, c = idx & 63;
    lw2t[(size_t)(n0 + n) * 64 + c] = f2bf(tile[c][n]);
  }
}

// ---- pre-pass 2: packed bias matrices ------------------------------------
__global__ void k_bias(const float* __restrict__ bw2, const float* __restrict__ lb2,
                       const float* __restrict__ bb2,
                       short* __restrict__ bb00, short* __restrict__ bb11,
                       short* __restrict__ bb01, short* __restrict__ bb10) {
  int r = blockIdx.x * 256 + threadIdx.x;
  if (r < 1024) {
    int uv = r;
    for (int k = 0; k < 64; ++k) bb00[uv * 96 + k] = f2bf(bw2[k * 1280 + uv]);
    for (int w = 0; w < 16; ++w) bb00[uv * 96 + 64 + w] = f2bf(lb2[w * 1024 + uv]);
    bb00[uv * 96 + 80] = f2bf(bb2[uv]);
    for (int k = 81; k < 96; ++k) bb00[uv * 96 + k] = 0;
  } else if (r < 1280) {
    int uv = r - 1024;
    for (int k = 0; k < 64; ++k) bb11[uv * 96 + k] = f2bf(bw2[k * 1280 + 1024 + uv]);
    for (int w = 0; w < 16; ++w) bb11[uv * 96 + 64 + w] = f2bf(lb2[16384 + w * 256 + uv]);
    bb11[uv * 96 + 80] = f2bf(bb2[1024 + uv]);
    for (int k = 81; k < 96; ++k) bb11[uv * 96 + k] = 0;
  } else if (r < 1792) {
    int uv = r - 1280;
    for (int w = 0; w < 16; ++w) bb01[uv * 32 + w] = f2bf(lb2[20480 + w * 512 + uv]);
    for (int k = 16; k < 32; ++k) bb01[uv * 32 + k] = 0;
  } else if (r < 2304) {
    int uv = r - 1792;
    for (int w = 0; w < 16; ++w) bb10[uv * 32 + w] = f2bf(lb2[28672 + w * 512 + uv]);
    for (int k = 16; k < 32; ++k) bb10[uv * 32 + k] = 0;
  }
}

// ---- pre-pass 3: per-sample h, h2, x0, x1 --------------------------------
__global__ void k_samples(const float* __restrict__ feat, const float* __restrict__ ne,
                          const float* __restrict__ W0, const float* __restrict__ W1,
                          const float* __restrict__ lw1, const float* __restrict__ lb1,
                          const float* __restrict__ bw1, const float* __restrict__ bb1,
                          float* __restrict__ H, float* __restrict__ H2,
                          float* __restrict__ X0, float* __restrict__ X1) {
  int b = blockIdx.x;
  int t = threadIdx.x;               // 192 threads
  __shared__ float sne[128];
  __shared__ float sf[320];
  if (t < 128) sne[t] = ne[(size_t)b * 128 + t];
  for (int i = t; i < 320; i += 192) sf[i] = feat[(size_t)b * 320 + i];
  __syncthreads();
  if (t < 64) {
    float a = lb1[t];
    for (int k = 0; k < 128; ++k) a += sne[k] * lw1[k * 64 + t];
    H[(size_t)b * 64 + t] = a / (1.0f + expf(-a));
  } else if (t < 128) {
    int c = t - 64;
    float a = bb1[c];
    for (int k = 0; k < 128; ++k) a += sne[k] * bw1[k * 64 + c];
    H2[(size_t)b * 64 + c] = a / (1.0f + expf(-a));
  } else if (t < 144) {
    int v = t - 128;
    float a = 0.0f;
    for (int u = 0; u < 128; ++u) a += sf[u] * W0[u * 16 + v];
    X0[(size_t)b * 16 + v] = a * 0.08838834764831845f;  // 1/sqrt(128)
  } else {
    int idx = t - 144, v = idx / 3, j = idx % 3;        // idx < 48
    float a = 0.0f;
    for (int u = 0; u < 64; ++u) a += sf[128 + u * 3 + j] * W1[u * 16 + v];
    X1[(size_t)b * 48 + v * 3 + j] = a * 0.125f;        // 1/sqrt(64)
  }
}

// ---- main kernel ----------------------------------------------------------
// Phase A helper: 2 sample-group Q-planes (stride 16384 shorts), NBIAS bias.
// Depth-4 B register pipeline; kk loop fully unrolled -> static buffer idx.
template <int N, int NOFF, int NSTR, int NBIAS, int BBW>
static __device__ __forceinline__ void mmA2(
    const short* __restrict__ LW2T, const short* __restrict__ BB,
    const short* __restrict__ sQp, const short* __restrict__ sAbp,
    int uvbase, int col, int q, f32x4 (&acc)[2][N]) {
  const short* lw = LW2T + (size_t)(NOFF + uvbase + col) * 64;
  const int aoff = (q * 16 + col) * 8;   // lane*16B: conflict-free
  auto bptr = [&](int kk, int i) -> const bf16x8* {
    return (const bf16x8*)(lw + ((size_t)(kk >> 1) * NSTR + i * 16) * 64 +
                           ((kk & 1) * 32 + q * 8));
  };
  bf16x8 B[4][N];
#pragma unroll
  for (int d = 0; d < 4; ++d)
#pragma unroll
    for (int i = 0; i < N; ++i) B[d][i] = *bptr(d, i);
#pragma unroll
  for (int kk = 0; kk < 32; ++kk) {
    const int d = kk & 3;
    const bf16x8 A0 = *(const bf16x8*)(sQp + kk * 512 + aoff);
    const bf16x8 A1 = *(const bf16x8*)(sQp + 16384 + kk * 512 + aoff);
#pragma unroll
    for (int i = 0; i < N; ++i) {
      acc[0][i] = __builtin_amdgcn_mfma_f32_16x16x32_bf16(A0, B[d][i], acc[0][i], 0, 0, 0);
      acc[1][i] = __builtin_amdgcn_mfma_f32_16x16x32_bf16(A1, B[d][i], acc[1][i], 0, 0, 0);
    }
    if (kk + 4 < 32) {
#pragma unroll
      for (int i = 0; i < N; ++i) B[d][i] = *bptr(kk + 4, i);
    }
  }
#pragma unroll
  for (int kk = 0; kk < NBIAS; ++kk) {
    const bf16x8 Ab0 = *(const bf16x8*)(sAbp + kk * 512 + aoff);
    const bf16x8 Ab1 = *(const bf16x8*)(sAbp + NBIAS * 512 + kk * 512 + aoff);
#pragma unroll
    for (int i = 0; i < N; ++i) {
      const bf16x8 Bx = *(const bf16x8*)(BB + (uvbase + i * 16 + col) * BBW + kk * 32 + q * 8);
      acc[0][i] = __builtin_amdgcn_mfma_f32_16x16x32_bf16(Ab0, Bx, acc[0][i], 0, 0, 0);
      acc[1][i] = __builtin_amdgcn_mfma_f32_16x16x32_bf16(Ab1, Bx, acc[1][i], 0, 0, 0);
    }
  }
}

// Phase B helper: NP Q-planes share each B load; depth-4 pipeline.
template <int NP, int N, int NOFF, int NSTR, int BBW>
static __device__ __forceinline__ void mmBnp(
    const short* __restrict__ LW2T, const short* __restrict__ BB,
    const short* __restrict__ sQp, const short* __restrict__ sA1p,
    int uvbase, int col, int q, f32x4 (&acc)[NP][N]) {
  const short* lw = LW2T + (size_t)(NOFF + uvbase + col) * 64;
  const int aoff = (q * 16 + col) * 8;
  auto bptr = [&](int kk, int i) -> const bf16x8* {
    return (const bf16x8*)(lw + ((size_t)(kk >> 1) * NSTR + i * 16) * 64 +
                           ((kk & 1) * 32 + q * 8));
  };
  bf16x8 B[4][N];
#pragma unroll
  for (int d = 0; d < 4; ++d)
#pragma unroll
    for (int i = 0; i < N; ++i) B[d][i] = *bptr(d, i);
#pragma unroll
  for (int kk = 0; kk < 32; ++kk) {
    const int d = kk & 3;
    bf16x8 A[NP];
#pragma unroll
    for (int p = 0; p < NP; ++p)
      A[p] = *(const bf16x8*)(sQp + p * 16384 + kk * 512 + aoff);
#pragma unroll
    for (int i = 0; i < N; ++i)
#pragma unroll
      for (int p = 0; p < NP; ++p)
        acc[p][i] = __builtin_amdgcn_mfma_f32_16x16x32_bf16(A[p], B[d][i], acc[p][i], 0, 0, 0);
    if (kk + 4 < 32) {
#pragma unroll
      for (int i = 0; i < N; ++i) B[d][i] = *bptr(kk + 4, i);
    }
  }
  // bias: k < 16 only; same B row for all planes
#pragma unroll
  for (int i = 0; i < N; ++i) {
    const bf16x8 Bx = *(const bf16x8*)(BB + (uvbase + i * 16 + col) * BBW + q * 8);
#pragma unroll
    for (int p = 0; p < NP; ++p) {
      const bf16x8 Ap = *(const bf16x8*)(sA1p + p * 512 + aoff);
      acc[p][i] = __builtin_amdgcn_mfma_f32_16x16x32_bf16(Ap, Bx, acc[p][i], 0, 0, 0);
    }
  }
}

__global__ __launch_bounds__(1024, 2) void k_main(
    const short* __restrict__ LW2T,
    const short* __restrict__ BB00, const short* __restrict__ BB11,
    const short* __restrict__ BB01, const short* __restrict__ BB10,
    const float* __restrict__ H, const float* __restrict__ H2,
    const float* __restrict__ X0, const float* __restrict__ X1,
    float* __restrict__ out) {
  constexpr float S00 = 0.0625f;                  // 1/16
  constexpr float S3 = 0.036084391824351614f;     // (1/sqrt(3))/16

  // blockIdx = slot + 8*seq, slot = (s&3) + 4*h  ->  XCD = slot:
  // XCDs 0..3 only read B-half 0, XCDs 4..7 only half 1 (2.36 MB each,
  // L2-resident).  h-split row boundaries are 128B-aligned -> no out-line
  // sharing across XCDs.
  int idx = blockIdx.x;
  int slot = idx & 7;
  int h = slot >> 2;
  int s = (slot & 3) + 4 * (idx >> 3);   // 0..127
  int b0 = s << 5;                        // 32 samples per tile
  int t = threadIdx.x;                    // 1024 threads = 16 waves
  int lane = t & 63, wave = t >> 6;
  int col = lane & 15, q = lane >> 4;

  __shared__ float sH[32][66];
  __shared__ float sX0[32][17];
  __shared__ float sX1[32][51];
  __shared__ short sQ[4][32][4][16][8];   // [plane][kk][q][col][e]
  __shared__ short sAb[2][3][4][16][8];   // phase-A bias planes per group
  __shared__ short sA1[3][2][4][16][8];   // phase-B bias planes [j][g]

  for (int i = t; i < 2048; i += 1024)
    sH[i >> 6][i & 63] = H[(size_t)(b0 + (i >> 6)) * 64 + (i & 63)];
  if (t < 512) sX0[t >> 4][t & 15] = X0[(size_t)(b0 + (t >> 4)) * 16 + (t & 15)];
  for (int i = t; i < 1536; i += 1024)
    sX1[i / 48][i % 48] = X1[(size_t)(b0 + i / 48) * 48 + (i % 48)];
  __syncthreads();

  // ===== build phase-A Q planes (g=0,1), sAb, sA1 =========================
  for (int i = t; i < 16384; i += 1024) {
    int p = i >> 13, rem = i & 8191;
    int kk = rem >> 8, qq = (rem >> 6) & 3, cc = (rem >> 2) & 15, e2 = (rem & 3) << 1;
    int k = kk * 32 + qq * 8 + e2;
    int w = k >> 6, c = k & 63;
    float xw = sX0[p * 16 + cc][w];
    unsigned lo = (unsigned short)f2bf(sH[p * 16 + cc][c] * xw);
    unsigned hi = (unsigned short)f2bf(sH[p * 16 + cc][c + 1] * xw);
    *(unsigned*)&sQ[p][kk][qq][cc][e2] = lo | (hi << 16);
  }
  for (int i = t; i < 3072; i += 1024) {   // sAb
    int g = (i >= 1536), rem = i - (g ? 1536 : 0);
    int kk = rem >> 9, r2 = rem & 511;
    int qq = r2 >> 7, cc = (r2 >> 3) & 15, e = r2 & 7;
    int k = kk * 32 + qq * 8 + e;
    float v = 0.0f;
    if (k < 64) v = H2[(size_t)(b0 + g * 16 + cc) * 64 + k];
    else if (k < 80) v = sX0[g * 16 + cc][k - 64];
    else if (k == 80) v = 1.0f;
    sAb[g][kk][qq][cc][e] = f2bf(v);
  }
  for (int i = t; i < 3072; i += 1024) {   // sA1 (all 3 j)
    int j = i >> 10, rem = i & 1023;
    int g = rem >> 9, r2 = rem & 511;
    int qq = r2 >> 7, cc = (r2 >> 3) & 15, e = r2 & 7;
    int k = qq * 8 + e;
    sA1[j][g][qq][cc][e] = (k < 16) ? f2bf(sX1[g * 16 + cc][k * 3 + j]) : (short)0;
  }
  __syncthreads();

  // ===== phase A: path00 (uv-half 512, wave owns 32) ======================
  {
    int uvbase = h * 512 + wave * 32;
    f32x4 acc[2][2] = {};
    mmA2<2, 0, 1024, 3, 96>(LW2T, BB00, &sQ[0][0][0][0][0], &sAb[0][0][0][0][0],
                            uvbase, col, q, acc);
#pragma unroll
    for (int g = 0; g < 2; ++g)
#pragma unroll
      for (int i = 0; i < 2; ++i)
#pragma unroll
        for (int ii = 0; ii < 4; ++ii) {
          size_t ob = (size_t)(b0 + g * 16 + q * 4 + ii) * 6400;
          int uv = uvbase + i * 16 + col;
          out[ob + (uv >> 5) * 80 + (uv & 31)] = acc[g][i][ii] * S00;
        }
  }
  // path11 (uv-half 128, waves 0..7 own 16 each)
  if (wave < 8) {
    int uvbase = h * 128 + wave * 16;
    f32x4 acc[2][1] = {};
    mmA2<1, 16384, 256, 3, 96>(LW2T, BB11, &sQ[0][0][0][0][0], &sAb[0][0][0][0][0],
                               uvbase, col, q, acc);
#pragma unroll
    for (int g = 0; g < 2; ++g)
#pragma unroll
      for (int ii = 0; ii < 4; ++ii) {
        size_t ob = (size_t)(b0 + g * 16 + q * 4 + ii) * 6400;
        int uv = uvbase + col;
        float val = acc[g][0][ii] * S3;
        int u = uv >> 4, v = uv & 15;
        float* p = out + ob + (size_t)(32 + 3 * u) * 80 + (32 + 3 * v);
        p[0] = val;   p[1] = 0.f;   p[2] = 0.f;
        p[80] = 0.f;  p[81] = val;  p[82] = 0.f;
        p[160] = 0.f; p[161] = 0.f; p[162] = val;
      }
  }

  // ===== phase B pass 1: planes (j,g) = (0,0),(0,1),(1,0),(1,1) ===========
  __syncthreads();
  for (int i = t; i < 32768; i += 1024) {
    int p = i >> 13, rem = i & 8191;
    int j = p >> 1, g = p & 1;
    int kk = rem >> 8, qq = (rem >> 6) & 3, cc = (rem >> 2) & 15, e2 = (rem & 3) << 1;
    int k = kk * 32 + qq * 8 + e2;
    int w = k >> 6, c = k & 63;
    float xw = sX1[g * 16 + cc][w * 3 + j];
    unsigned lo = (unsigned short)f2bf(sH[g * 16 + cc][c] * xw);
    unsigned hi = (unsigned short)f2bf(sH[g * 16 + cc][c + 1] * xw);
    *(unsigned*)&sQ[p][kk][qq][cc][e2] = lo | (hi << 16);
  }
  __syncthreads();
  {
    int uvbase = h * 256 + wave * 16;
    {
      f32x4 acc[4][1] = {};
      mmBnp<4, 1, 20480, 512, 32>(LW2T, BB01, &sQ[0][0][0][0][0],
                                  &sA1[0][0][0][0][0], uvbase, col, q, acc);
#pragma unroll
      for (int p = 0; p < 4; ++p)
#pragma unroll
        for (int ii = 0; ii < 4; ++ii) {
          int j = p >> 1, g = p & 1;
          size_t ob = (size_t)(b0 + g * 16 + q * 4 + ii) * 6400;
          int uv = uvbase + col;
          out[ob + (uv >> 4) * 80 + 32 + 3 * (uv & 15) + j] = acc[p][0][ii] * S3;
        }
    }
    {
      f32x4 acc[4][1] = {};
      mmBnp<4, 1, 28672, 512, 32>(LW2T, BB10, &sQ[0][0][0][0][0],
                                  &sA1[0][0][0][0][0], uvbase, col, q, acc);
#pragma unroll
      for (int p = 0; p < 4; ++p)
#pragma unroll
        for (int ii = 0; ii < 4; ++ii) {
          int j = p >> 1, g = p & 1;
          size_t ob = (size_t)(b0 + g * 16 + q * 4 + ii) * 6400;
          int uv = uvbase + col;
          out[ob + (size_t)(32 + 3 * (uv >> 5) + j) * 80 + (uv & 31)] = acc[p][0][ii] * S3;
        }
    }
  }

  // ===== phase B pass 2: planes g = 0,1 at j = 2 ==========================
  __syncthreads();
  for (int i = t; i < 16384; i += 1024) {
    int g = i >> 13, rem = i & 8191;
    int kk = rem >> 8, qq = (rem >> 6) & 3, cc = (rem >> 2) & 15, e2 = (rem & 3) << 1;
    int k = kk * 32 + qq * 8 + e2;
    int w = k >> 6, c = k & 63;
    float xw = sX1[g * 16 + cc][w * 3 + 2];
    unsigned lo = (unsigned short)f2bf(sH[g * 16 + cc][c] * xw);
    unsigned hi = (unsigned short)f2bf(sH[g * 16 + cc][c + 1] * xw);
    *(unsigned*)&sQ[g][kk][qq][cc][e2] = lo | (hi << 16);
  }
  __syncthreads();
  {
    int uvbase = h * 256 + wave * 16;
    {
      f32x4 acc[2][1] = {};
      mmBnp<2, 1, 20480, 512, 32>(LW2T, BB01, &sQ[0][0][0][0][0],
                                  &sA1[2][0][0][0][0], uvbase, col, q, acc);
#pragma unroll
      for (int g = 0; g < 2; ++g)
#pragma unroll
        for (int ii = 0; ii < 4; ++ii) {
          size_t ob = (size_t)(b0 + g * 16 + q * 4 + ii) * 6400;
          int uv = uvbase + col;
          out[ob + (uv >> 4) * 80 + 32 + 3 * (uv & 15) + 2] = acc[g][0][ii] * S3;
        }
    }
    {
      f32x4 acc[2][1] = {};
      mmBnp<2, 1, 28672, 512, 32>(LW2T, BB10, &sQ[0][0][0][0][0],
                                  &sA1[2][0][0][0][0], uvbase, col, q, acc);
#pragma unroll
      for (int g = 0; g < 2; ++g)
#pragma unroll
        for (int ii = 0; ii < 4; ++ii) {
          size_t ob = (size_t)(b0 + g * 16 + q * 4 + ii) * 6400;
          int uv = uvbase + col;
          out[ob + (size_t)(32 + 3 * (uv >> 5) + 2) * 80 + (uv & 31)] = acc[g][0][ii] * S3;
        }
    }
  }
}

// ---------------------------------------------------------------------------
extern "C" void kernel_launch(void* const* d_in, const int* in_sizes, int n_in,
                              void* d_out, int out_size, void* d_ws, size_t ws_size,
                              hipStream_t stream) {
  const float* feat = (const float*)d_in[0];
  const float* ne   = (const float*)d_in[1];
  const float* W0   = (const float*)d_in[2];
  const float* W1   = (const float*)d_in[3];
  const float* lw1  = (const float*)d_in[4];
  const float* lb1  = (const float*)d_in[5];
  const float* lw2  = (const float*)d_in[6];
  const float* lb2  = (const float*)d_in[7];
  const float* bw1  = (const float*)d_in[8];
  const float* bb1  = (const float*)d_in[9];
  const float* bw2  = (const float*)d_in[10];
  const float* bb2  = (const float*)d_in[11];

  char* ws = (char*)d_ws;
  short* LW2T = (short*)ws; ws += (size_t)36864 * 64 * 2;   // 4.72 MB
  short* BB00 = (short*)ws; ws += (size_t)1024 * 96 * 2;
  short* BB11 = (short*)ws; ws += (size_t)256 * 96 * 2;
  short* BB01 = (short*)ws; ws += (size_t)512 * 32 * 2;
  short* BB10 = (short*)ws; ws += (size_t)512 * 32 * 2;
  float* H  = (float*)ws;   ws += (size_t)4096 * 64 * 4;
  float* H2 = (float*)ws;   ws += (size_t)4096 * 64 * 4;
  float* X0 = (float*)ws;   ws += (size_t)4096 * 16 * 4;
  float* X1 = (float*)ws;   ws += (size_t)4096 * 48 * 4;
  (void)ws_size; (void)in_sizes; (void)n_in; (void)out_size;

  hipLaunchKernelGGL(k_transpose, dim3(576), dim3(256), 0, stream, lw2, LW2T);
  hipLaunchKernelGGL(k_bias, dim3(9), dim3(256), 0, stream, bw2, lb2, bb2,
                     BB00, BB11, BB01, BB10);
  hipLaunchKernelGGL(k_samples, dim3(4096), dim3(192), 0, stream,
                     feat, ne, W0, W1, lw1, lb1, bw1, bb1, H, H2, X0, X1);
  hipLaunchKernelGGL(k_main, dim3(256), dim3(1024), 0, stream,
                     LW2T, BB00, BB11, BB01, BB10, H, H2, X0, X1, (float*)d_out);
}

// Round 15
// 212.395 us; speedup vs baseline: 1.0113x; 1.0113x over previous
//
#include <hip/hip_runtime.h>
#include <hip/hip_bf16.h>
#include <math.h>

// ---------------------------------------------------------------------------
// Expansion kernel.  Q-form fusion: out[b,uv] = sum_k Q[b,k]*LW2T[n(uv),k]
// Round 15: round-14 source with ONE change: amdgpu_waves_per_eu(4,4).
// Rounds 13/14 proved the allocator targets max-theoretical-occupancy
// IGNORING the LDS limit: a 1024-thread block could co-reside twice at
// VGPR<=64, so it picked 64 and spilled (WRITE 270MB = 103 out + 167
// spill; 374MB at 1.8TB/s HBM == the whole 208us -> the 16-wave variant
// is HBM-bound on SPILL traffic).  Our 157KB LDS pins 1 block/CU = 4
// waves/EU, where 128 VGPR is free.  waves_per_eu(4,4): min=4 -> cap
// 512/4=128; max=4 forbids the 8-waves/EU register sacrifice.
// Everything else byte-identical to round 14 (passing).
// ---------------------------------------------------------------------------

typedef short bf16x8 __attribute__((ext_vector_type(8)));
typedef float f32x4 __attribute__((ext_vector_type(4)));

static __device__ __forceinline__ short f2bf(float f) {
  unsigned u = __builtin_bit_cast(unsigned, f);
  u = u + 0x7fffu + ((u >> 16) & 1u);   // round-to-nearest-even
  return (short)(u >> 16);
}

// ---- pre-pass 1: LW2 [64][36864] f32 -> LW2T bf16 [36864][64] ------------
__global__ void k_transpose(const float* __restrict__ lw2, short* __restrict__ lw2t) {
  __shared__ float tile[64][65];
  int n0 = blockIdx.x * 64;
  int t = threadIdx.x;
#pragma unroll
  for (int k = 0; k < 16; ++k) {
    int idx = k * 256 + t;
    int c = idx >> 6, j = idx & 63;
    tile[c][j] = lw2[(size_t)c * 36864 + n0 + j];
  }
  __syncthreads();
#pragma unroll
  for (int k = 0; k < 16; ++k) {
    int idx = k * 256 + t;
    int n = idx >> 6, c = idx & 63;
    lw2t[(size_t)(n0 + n) * 64 + c] = f2bf(tile[c][n]);
  }
}

// ---- pre-pass 2: packed bias matrices ------------------------------------
__global__ void k_bias(const float* __restrict__ bw2, const float* __restrict__ lb2,
                       const float* __restrict__ bb2,
                       short* __restrict__ bb00, short* __restrict__ bb11,
                       short* __restrict__ bb01, short* __restrict__ bb10) {
  int r = blockIdx.x * 256 + threadIdx.x;
  if (r < 1024) {
    int uv = r;
    for (int k = 0; k < 64; ++k) bb00[uv * 96 + k] = f2bf(bw2[k * 1280 + uv]);
    for (int w = 0; w < 16; ++w) bb00[uv * 96 + 64 + w] = f2bf(lb2[w * 1024 + uv]);
    bb00[uv * 96 + 80] = f2bf(bb2[uv]);
    for (int k = 81; k < 96; ++k) bb00[uv * 96 + k] = 0;
  } else if (r < 1280) {
    int uv = r - 1024;
    for (int k = 0; k < 64; ++k) bb11[uv * 96 + k] = f2bf(bw2[k * 1280 + 1024 + uv]);
    for (int w = 0; w < 16; ++w) bb11[uv * 96 + 64 + w] = f2bf(lb2[16384 + w * 256 + uv]);
    bb11[uv * 96 + 80] = f2bf(bb2[1024 + uv]);
    for (int k = 81; k < 96; ++k) bb11[uv * 96 + k] = 0;
  } else if (r < 1792) {
    int uv = r - 1280;
    for (int w = 0; w < 16; ++w) bb01[uv * 32 + w] = f2bf(lb2[20480 + w * 512 + uv]);
    for (int k = 16; k < 32; ++k) bb01[uv * 32 + k] = 0;
  } else if (r < 2304) {
    int uv = r - 1792;
    for (int w = 0; w < 16; ++w) bb10[uv * 32 + w] = f2bf(lb2[28672 + w * 512 + uv]);
    for (int k = 16; k < 32; ++k) bb10[uv * 32 + k] = 0;
  }
}

// ---- pre-pass 3: per-sample h, h2, x0, x1 --------------------------------
__global__ void k_samples(const float* __restrict__ feat, const float* __restrict__ ne,
                          const float* __restrict__ W0, const float* __restrict__ W1,
                          const float* __restrict__ lw1, const float* __restrict__ lb1,
                          const float* __restrict__ bw1, const float* __restrict__ bb1,
                          float* __restrict__ H, float* __restrict__ H2,
                          float* __restrict__ X0, float* __restrict__ X1) {
  int b = blockIdx.x;
  int t = threadIdx.x;               // 192 threads
  __shared__ float sne[128];
  __shared__ float sf[320];
  if (t < 128) sne[t] = ne[(size_t)b * 128 + t];
  for (int i = t; i < 320; i += 192) sf[i] = feat[(size_t)b * 320 + i];
  __syncthreads();
  if (t < 64) {
    float a = lb1[t];
    for (int k = 0; k < 128; ++k) a += sne[k] * lw1[k * 64 + t];
    H[(size_t)b * 64 + t] = a / (1.0f + expf(-a));
  } else if (t < 128) {
    int c = t - 64;
    float a = bb1[c];
    for (int k = 0; k < 128; ++k) a += sne[k] * bw1[k * 64 + c];
    H2[(size_t)b * 64 + c] = a / (1.0f + expf(-a));
  } else if (t < 144) {
    int v = t - 128;
    float a = 0.0f;
    for (int u = 0; u < 128; ++u) a += sf[u] * W0[u * 16 + v];
    X0[(size_t)b * 16 + v] = a * 0.08838834764831845f;  // 1/sqrt(128)
  } else {
    int idx = t - 144, v = idx / 3, j = idx % 3;        // idx < 48
    float a = 0.0f;
    for (int u = 0; u < 64; ++u) a += sf[128 + u * 3 + j] * W1[u * 16 + v];
    X1[(size_t)b * 48 + v * 3 + j] = a * 0.125f;        // 1/sqrt(64)
  }
}

// ---- main kernel ----------------------------------------------------------
// Phase A helper: 2 sample-group Q-planes (stride 16384 shorts), NBIAS bias.
// Depth-4 B register pipeline; kk loop fully unrolled -> static buffer idx.
template <int N, int NOFF, int NSTR, int NBIAS, int BBW>
static __device__ __forceinline__ void mmA2(
    const short* __restrict__ LW2T, const short* __restrict__ BB,
    const short* __restrict__ sQp, const short* __restrict__ sAbp,
    int uvbase, int col, int q, f32x4 (&acc)[2][N]) {
  const short* lw = LW2T + (size_t)(NOFF + uvbase + col) * 64;
  const int aoff = (q * 16 + col) * 8;   // lane*16B: conflict-free
  auto bptr = [&](int kk, int i) -> const bf16x8* {
    return (const bf16x8*)(lw + ((size_t)(kk >> 1) * NSTR + i * 16) * 64 +
                           ((kk & 1) * 32 + q * 8));
  };
  bf16x8 B[4][N];
#pragma unroll
  for (int d = 0; d < 4; ++d)
#pragma unroll
    for (int i = 0; i < N; ++i) B[d][i] = *bptr(d, i);
#pragma unroll
  for (int kk = 0; kk < 32; ++kk) {
    const int d = kk & 3;
    const bf16x8 A0 = *(const bf16x8*)(sQp + kk * 512 + aoff);
    const bf16x8 A1 = *(const bf16x8*)(sQp + 16384 + kk * 512 + aoff);
#pragma unroll
    for (int i = 0; i < N; ++i) {
      acc[0][i] = __builtin_amdgcn_mfma_f32_16x16x32_bf16(A0, B[d][i], acc[0][i], 0, 0, 0);
      acc[1][i] = __builtin_amdgcn_mfma_f32_16x16x32_bf16(A1, B[d][i], acc[1][i], 0, 0, 0);
    }
    if (kk + 4 < 32) {
#pragma unroll
      for (int i = 0; i < N; ++i) B[d][i] = *bptr(kk + 4, i);
    }
  }
#pragma unroll
  for (int kk = 0; kk < NBIAS; ++kk) {
    const bf16x8 Ab0 = *(const bf16x8*)(sAbp + kk * 512 + aoff);
    const bf16x8 Ab1 = *(const bf16x8*)(sAbp + NBIAS * 512 + kk * 512 + aoff);
#pragma unroll
    for (int i = 0; i < N; ++i) {
      const bf16x8 Bx = *(const bf16x8*)(BB + (uvbase + i * 16 + col) * BBW + kk * 32 + q * 8);
      acc[0][i] = __builtin_amdgcn_mfma_f32_16x16x32_bf16(Ab0, Bx, acc[0][i], 0, 0, 0);
      acc[1][i] = __builtin_amdgcn_mfma_f32_16x16x32_bf16(Ab1, Bx, acc[1][i], 0, 0, 0);
    }
  }
}

// Phase B helper: NP Q-planes share each B load; depth-4 pipeline.
template <int NP, int N, int NOFF, int NSTR, int BBW>
static __device__ __forceinline__ void mmBnp(
    const short* __restrict__ LW2T, const short* __restrict__ BB,
    const short* __restrict__ sQp, const short* __restrict__ sA1p,
    int uvbase, int col, int q, f32x4 (&acc)[NP][N]) {
  const short* lw = LW2T + (size_t)(NOFF + uvbase + col) * 64;
  const int aoff = (q * 16 + col) * 8;
  auto bptr = [&](int kk, int i) -> const bf16x8* {
    return (const bf16x8*)(lw + ((size_t)(kk >> 1) * NSTR + i * 16) * 64 +
                           ((kk & 1) * 32 + q * 8));
  };
  bf16x8 B[4][N];
#pragma unroll
  for (int d = 0; d < 4; ++d)
#pragma unroll
    for (int i = 0; i < N; ++i) B[d][i] = *bptr(d, i);
#pragma unroll
  for (int kk = 0; kk < 32; ++kk) {
    const int d = kk & 3;
    bf16x8 A[NP];
#pragma unroll
    for (int p = 0; p < NP; ++p)
      A[p] = *(const bf16x8*)(sQp + p * 16384 + kk * 512 + aoff);
#pragma unroll
    for (int i = 0; i < N; ++i)
#pragma unroll
      for (int p = 0; p < NP; ++p)
        acc[p][i] = __builtin_amdgcn_mfma_f32_16x16x32_bf16(A[p], B[d][i], acc[p][i], 0, 0, 0);
    if (kk + 4 < 32) {
#pragma unroll
      for (int i = 0; i < N; ++i) B[d][i] = *bptr(kk + 4, i);
    }
  }
  // bias: k < 16 only; same B row for all planes
#pragma unroll
  for (int i = 0; i < N; ++i) {
    const bf16x8 Bx = *(const bf16x8*)(BB + (uvbase + i * 16 + col) * BBW + q * 8);
#pragma unroll
    for (int p = 0; p < NP; ++p) {
      const bf16x8 Ap = *(const bf16x8*)(sA1p + p * 512 + aoff);
      acc[p][i] = __builtin_amdgcn_mfma_f32_16x16x32_bf16(Ap, Bx, acc[p][i], 0, 0, 0);
    }
  }
}

__global__ __launch_bounds__(1024)
__attribute__((amdgpu_waves_per_eu(4, 4)))
void k_main(
    const short* __restrict__ LW2T,
    const short* __restrict__ BB00, const short* __restrict__ BB11,
    const short* __restrict__ BB01, const short* __restrict__ BB10,
    const float* __restrict__ H, const float* __restrict__ H2,
    const float* __restrict__ X0, const float* __restrict__ X1,
    float* __restrict__ out) {
  constexpr float S00 = 0.0625f;                  // 1/16
  constexpr float S3 = 0.036084391824351614f;     // (1/sqrt(3))/16

  // blockIdx = slot + 8*seq, slot = (s&3) + 4*h  ->  XCD = slot:
  // XCDs 0..3 only read B-half 0, XCDs 4..7 only half 1 (2.36 MB each,
  // L2-resident).  h-split row boundaries are 128B-aligned -> no out-line
  // sharing across XCDs.
  int idx = blockIdx.x;
  int slot = idx & 7;
  int h = slot >> 2;
  int s = (slot & 3) + 4 * (idx >> 3);   // 0..127
  int b0 = s << 5;                        // 32 samples per tile
  int t = threadIdx.x;                    // 1024 threads = 16 waves
  int lane = t & 63, wave = t >> 6;
  int col = lane & 15, q = lane >> 4;

  __shared__ float sH[32][66];
  __shared__ float sX0[32][17];
  __shared__ float sX1[32][51];
  __shared__ short sQ[4][32][4][16][8];   // [plane][kk][q][col][e]
  __shared__ short sAb[2][3][4][16][8];   // phase-A bias planes per group
  __shared__ short sA1[3][2][4][16][8];   // phase-B bias planes [j][g]

  for (int i = t; i < 2048; i += 1024)
    sH[i >> 6][i & 63] = H[(size_t)(b0 + (i >> 6)) * 64 + (i & 63)];
  if (t < 512) sX0[t >> 4][t & 15] = X0[(size_t)(b0 + (t >> 4)) * 16 + (t & 15)];
  for (int i = t; i < 1536; i += 1024)
    sX1[i / 48][i % 48] = X1[(size_t)(b0 + i / 48) * 48 + (i % 48)];
  __syncthreads();

  // ===== build phase-A Q planes (g=0,1), sAb, sA1 =========================
  for (int i = t; i < 16384; i += 1024) {
    int p = i >> 13, rem = i & 8191;
    int kk = rem >> 8, qq = (rem >> 6) & 3, cc = (rem >> 2) & 15, e2 = (rem & 3) << 1;
    int k = kk * 32 + qq * 8 + e2;
    int w = k >> 6, c = k & 63;
    float xw = sX0[p * 16 + cc][w];
    unsigned lo = (unsigned short)f2bf(sH[p * 16 + cc][c] * xw);
    unsigned hi = (unsigned short)f2bf(sH[p * 16 + cc][c + 1] * xw);
    *(unsigned*)&sQ[p][kk][qq][cc][e2] = lo | (hi << 16);
  }
  for (int i = t; i < 3072; i += 1024) {   // sAb
    int g = (i >= 1536), rem = i - (g ? 1536 : 0);
    int kk = rem >> 9, r2 = rem & 511;
    int qq = r2 >> 7, cc = (r2 >> 3) & 15, e = r2 & 7;
    int k = kk * 32 + qq * 8 + e;
    float v = 0.0f;
    if (k < 64) v = H2[(size_t)(b0 + g * 16 + cc) * 64 + k];
    else if (k < 80) v = sX0[g * 16 + cc][k - 64];
    else if (k == 80) v = 1.0f;
    sAb[g][kk][qq][cc][e] = f2bf(v);
  }
  for (int i = t; i < 3072; i += 1024) {   // sA1 (all 3 j)
    int j = i >> 10, rem = i & 1023;
    int g = rem >> 9, r2 = rem & 511;
    int qq = r2 >> 7, cc = (r2 >> 3) & 15, e = r2 & 7;
    int k = qq * 8 + e;
    sA1[j][g][qq][cc][e] = (k < 16) ? f2bf(sX1[g * 16 + cc][k * 3 + j]) : (short)0;
  }
  __syncthreads();

  // ===== phase A: path00 (uv-half 512, wave owns 32) ======================
  {
    int uvbase = h * 512 + wave * 32;
    f32x4 acc[2][2] = {};
    mmA2<2, 0, 1024, 3, 96>(LW2T, BB00, &sQ[0][0][0][0][0], &sAb[0][0][0][0][0],
                            uvbase, col, q, acc);
#pragma unroll
    for (int g = 0; g < 2; ++g)
#pragma unroll
      for (int i = 0; i < 2; ++i)
#pragma unroll
        for (int ii = 0; ii < 4; ++ii) {
          size_t ob = (size_t)(b0 + g * 16 + q * 4 + ii) * 6400;
          int uv = uvbase + i * 16 + col;
          out[ob + (uv >> 5) * 80 + (uv & 31)] = acc[g][i][ii] * S00;
        }
  }
  // path11 (uv-half 128, waves 0..7 own 16 each)
  if (wave < 8) {
    int uvbase = h * 128 + wave * 16;
    f32x4 acc[2][1] = {};
    mmA2<1, 16384, 256, 3, 96>(LW2T, BB11, &sQ[0][0][0][0][0], &sAb[0][0][0][0][0],
                               uvbase, col, q, acc);
#pragma unroll
    for (int g = 0; g < 2; ++g)
#pragma unroll
      for (int ii = 0; ii < 4; ++ii) {
        size_t ob = (size_t)(b0 + g * 16 + q * 4 + ii) * 6400;
        int uv = uvbase + col;
        float val = acc[g][0][ii] * S3;
        int u = uv >> 4, v = uv & 15;
        float* p = out + ob + (size_t)(32 + 3 * u) * 80 + (32 + 3 * v);
        p[0] = val;   p[1] = 0.f;   p[2] = 0.f;
        p[80] = 0.f;  p[81] = val;  p[82] = 0.f;
        p[160] = 0.f; p[161] = 0.f; p[162] = val;
      }
  }

  // ===== phase B pass 1: planes (j,g) = (0,0),(0,1),(1,0),(1,1) ===========
  __syncthreads();
  for (int i = t; i < 32768; i += 1024) {
    int p = i >> 13, rem = i & 8191;
    int j = p >> 1, g = p & 1;
    int kk = rem >> 8, qq = (rem >> 6) & 3, cc = (rem >> 2) & 15, e2 = (rem & 3) << 1;
    int k = kk * 32 + qq * 8 + e2;
    int w = k >> 6, c = k & 63;
    float xw = sX1[g * 16 + cc][w * 3 + j];
    unsigned lo = (unsigned short)f2bf(sH[g * 16 + cc][c] * xw);
    unsigned hi = (unsigned short)f2bf(sH[g * 16 + cc][c + 1] * xw);
    *(unsigned*)&sQ[p][kk][qq][cc][e2] = lo | (hi << 16);
  }
  __syncthreads();
  {
    int uvbase = h * 256 + wave * 16;
    {
      f32x4 acc[4][1] = {};
      mmBnp<4, 1, 20480, 512, 32>(LW2T, BB01, &sQ[0][0][0][0][0],
                                  &sA1[0][0][0][0][0], uvbase, col, q, acc);
#pragma unroll
      for (int p = 0; p < 4; ++p)
#pragma unroll
        for (int ii = 0; ii < 4; ++ii) {
          int j = p >> 1, g = p & 1;
          size_t ob = (size_t)(b0 + g * 16 + q * 4 + ii) * 6400;
          int uv = uvbase + col;
          out[ob + (uv >> 4) * 80 + 32 + 3 * (uv & 15) + j] = acc[p][0][ii] * S3;
        }
    }
    {
      f32x4 acc[4][1] = {};
      mmBnp<4, 1, 28672, 512, 32>(LW2T, BB10, &sQ[0][0][0][0][0],
                                  &sA1[0][0][0][0][0], uvbase, col, q, acc);
#pragma unroll
      for (int p = 0; p < 4; ++p)
#pragma unroll
        for (int ii = 0; ii < 4; ++ii) {
          int j = p >> 1, g = p & 1;
          size_t ob = (size_t)(b0 + g * 16 + q * 4 + ii) * 6400;
          int uv = uvbase + col;
          out[ob + (size_t)(32 + 3 * (uv >> 5) + j) * 80 + (uv & 31)] = acc[p][0][ii] * S3;
        }
    }
  }

  // ===== phase B pass 2: planes g = 0,1 at j = 2 ==========================
  __syncthreads();
  for (int i = t; i < 16384; i += 1024) {
    int g = i >> 13, rem = i & 8191;
    int kk = rem >> 8, qq = (rem >> 6) & 3, cc = (rem >> 2) & 15, e2 = (rem & 3) << 1;
    int k = kk * 32 + qq * 8 + e2;
    int w = k >> 6, c = k & 63;
    float xw = sX1[g * 16 + cc][w * 3 + 2];
    unsigned lo = (unsigned short)f2bf(sH[g * 16 + cc][c] * xw);
    unsigned hi = (unsigned short)f2bf(sH[g * 16 + cc][c + 1] * xw);
    *(unsigned*)&sQ[g][kk][qq][cc][e2] = lo | (hi << 16);
  }
  __syncthreads();
  {
    int uvbase = h * 256 + wave * 16;
    {
      f32x4 acc[2][1] = {};
      mmBnp<2, 1, 20480, 512, 32>(LW2T, BB01, &sQ[0][0][0][0][0],
                                  &sA1[2][0][0][0][0], uvbase, col, q, acc);
#pragma unroll
      for (int g = 0; g < 2; ++g)
#pragma unroll
        for (int ii = 0; ii < 4; ++ii) {
          size_t ob = (size_t)(b0 + g * 16 + q * 4 + ii) * 6400;
          int uv = uvbase + col;
          out[ob + (uv >> 4) * 80 + 32 + 3 * (uv & 15) + 2] = acc[g][0][ii] * S3;
        }
    }
    {
      f32x4 acc[2][1] = {};
      mmBnp<2, 1, 28672, 512, 32>(LW2T, BB10, &sQ[0][0][0][0][0],
                                  &sA1[2][0][0][0][0], uvbase, col, q, acc);
#pragma unroll
      for (int g = 0; g < 2; ++g)
#pragma unroll
        for (int ii = 0; ii < 4; ++ii) {
          size_t ob = (size_t)(b0 + g * 16 + q * 4 + ii) * 6400;
          int uv = uvbase + col;
          out[ob + (size_t)(32 + 3 * (uv >> 5) + 2) * 80 + (uv & 31)] = acc[g][0][ii] * S3;
        }
    }
  }
}

// ---------------------------------------------------------------------------
extern "C" void kernel_launch(void* const* d_in, const int* in_sizes, int n_in,
                              void* d_out, int out_size, void* d_ws, size_t ws_size,
                              hipStream_t stream) {
  const float* feat = (const float*)d_in[0];
  const float* ne   = (const float*)d_in[1];
  const float* W0   = (const float*)d_in[2];
  const float* W1   = (const float*)d_in[3];
  const float* lw1  = (const float*)d_in[4];
  const float* lb1  = (const float*)d_in[5];
  const float* lw2  = (const float*)d_in[6];
  const float* lb2  = (const float*)d_in[7];
  const float* bw1  = (const float*)d_in[8];
  const float* bb1  = (const float*)d_in[9];
  const float* bw2  = (const float*)d_in[10];
  const float* bb2  = (const float*)d_in[11];

  char* ws = (char*)d_ws;
  short* LW2T = (short*)ws; ws += (size_t)36864 * 64 * 2;   // 4.72 MB
  short* BB00 = (short*)ws; ws += (size_t)1024 * 96 * 2;
  short* BB11 = (short*)ws; ws += (size_t)256 * 96 * 2;
  short* BB01 = (short*)ws; ws += (size_t)512 * 32 * 2;
  short* BB10 = (short*)ws; ws += (size_t)512 * 32 * 2;
  float* H  = (float*)ws;   ws += (size_t)4096 * 64 * 4;
  float* H2 = (float*)ws;   ws += (size_t)4096 * 64 * 4;
  float* X0 = (float*)ws;   ws += (size_t)4096 * 16 * 4;
  float* X1 = (float*)ws;   ws += (size_t)4096 * 48 * 4;
  (void)ws_size; (void)in_sizes; (void)n_in; (void)out_size;

  hipLaunchKernelGGL(k_transpose, dim3(576), dim3(256), 0, stream, lw2, LW2T);
  hipLaunchKernelGGL(k_bias, dim3(9), dim3(256), 0, stream, bw2, lb2, bb2,
                     BB00, BB11, BB01, BB10);
  hipLaunchKernelGGL(k_samples, dim3(4096), dim3(192), 0, stream,
                     feat, ne, W0, W1, lw1, lb1, bw1, bb1, H, H2, X0, X1);
  hipLaunchKernelGGL(k_main, dim3(256), dim3(1024), 0, stream,
                     LW2T, BB00, BB11, BB01, BB10, H, H2, X0, X1, (float*)d_out);
}

// Round 16
// 138.258 us; speedup vs baseline: 1.5536x; 1.5362x over previous
//
#include <hip/hip_runtime.h>
#include <hip/hip_bf16.h>
#include <math.h>

// ---------------------------------------------------------------------------
// Expansion kernel.  Q-form fusion: out[b,uv] = sum_k Q[b,k]*LW2T[n(uv),k]
// Round 16: round-10 structure (512 thr, VGPR 128, depth-4, XCD-half
// affinity -- last good perf, k_main 155us) + FRAGMENT-CONTIGUOUS B layout.
// Round 9/10 B loads read 16 rows x half-lines per wave instruction (16
// 128B-line requests, each half-used) -> ~16cy L1/TA occupancy per load,
// ~50k cy/CU of L1 serialization stacked under L2 latency.  New layout:
// LW2F[(nb*2+half)][lane][8] where nb=row/16, half=col-half, lane=q*16+col
// -- each wave load is ONE contiguous 1KB burst (8 fully-used lines,
// lane*16B).  Bias matrices fragment-reordered identically (same sizes).
// k_main addressing: frag*1024B + lane*16B.  Rounds 13-15 closed the
// 1024-thread TLP avenue (allocator pins VGPR=64 and spills, 208us).
// ---------------------------------------------------------------------------

typedef short bf16x8 __attribute__((ext_vector_type(8)));
typedef float f32x4 __attribute__((ext_vector_type(4)));

static __device__ __forceinline__ short f2bf(float f) {
  unsigned u = __builtin_bit_cast(unsigned, f);
  u = u + 0x7fffu + ((u >> 16) & 1u);   // round-to-nearest-even
  return (short)(u >> 16);
}

// ---- pre-pass 1: LW2 [64][36864] f32 -> LW2F fragment layout -------------
// fragment (nb = n>>4, half) : 64 lanes (l = q*16+colr) x 8 bf16
//   element: row n = nb*16 + (l&15), col c = half*32 + (l>>4)*8 + e
__global__ void k_transpose(const float* __restrict__ lw2, short* __restrict__ lw2f) {
  __shared__ float tile[64][65];
  int n0 = blockIdx.x * 64;
  int t = threadIdx.x;
#pragma unroll
  for (int k = 0; k < 16; ++k) {
    int idx = k * 256 + t;
    int c = idx >> 6, j = idx & 63;
    tile[c][j] = lw2[(size_t)c * 36864 + n0 + j];
  }
  __syncthreads();
#pragma unroll
  for (int k = 0; k < 16; ++k) {
    int idx = k * 256 + t;
    int e = idx & 7, l = (idx >> 3) & 63, half = (idx >> 9) & 1, nbl = idx >> 10;
    int q = l >> 4, colr = l & 15;
    int j = nbl * 16 + colr;
    int c = half * 32 + q * 8 + e;
    size_t nb = (size_t)(n0 >> 4) + nbl;
    lw2f[((nb * 2 + half) * 64 + l) * 8 + e] = f2bf(tile[c][j]);
  }
}

// ---- pre-pass 2: fragment-layout bias matrices ----------------------------
// BBF00: 64 uvb x 3 kk x 512   (rows uv<1024, cols k = kk*32+q*8+e)
// BBF11: 16 uvb x 3 kk x 512   (rows uv<256)
// BBF01: 32 uvb x 1 x 512      (rows uv<512, k = q*8+e < 32)
// BBF10: 32 uvb x 1 x 512
__global__ void k_bias(const float* __restrict__ bw2, const float* __restrict__ lb2,
                       const float* __restrict__ bb2,
                       short* __restrict__ bbf00, short* __restrict__ bbf11,
                       short* __restrict__ bbf01, short* __restrict__ bbf10) {
  int i = blockIdx.x * 256 + threadIdx.x;
  if (i < 98304) {                       // BBF00
    int uvb = i / 1536, r = i % 1536;
    int kk = r >> 9, l = (r >> 3) & 63, e = r & 7;
    int q = l >> 4, col = l & 15;
    int uv = uvb * 16 + col, k = kk * 32 + q * 8 + e;
    float v = 0.0f;
    if (k < 64) v = bw2[k * 1280 + uv];
    else if (k < 80) v = lb2[(k - 64) * 1024 + uv];
    else if (k == 80) v = bb2[uv];
    bbf00[i] = f2bf(v);
  } else if (i < 122880) {               // BBF11
    int j = i - 98304;
    int uvb = j / 1536, r = j % 1536;
    int kk = r >> 9, l = (r >> 3) & 63, e = r & 7;
    int q = l >> 4, col = l & 15;
    int uv = uvb * 16 + col, k = kk * 32 + q * 8 + e;
    float v = 0.0f;
    if (k < 64) v = bw2[k * 1280 + 1024 + uv];
    else if (k < 80) v = lb2[16384 + (k - 64) * 256 + uv];
    else if (k == 80) v = bb2[1024 + uv];
    bbf11[j] = f2bf(v);
  } else if (i < 139264) {               // BBF01
    int j = i - 122880;
    int uvb = j >> 9, r = j & 511;
    int l = (r >> 3) & 63, e = r & 7;
    int q = l >> 4, col = l & 15;
    int uv = uvb * 16 + col, k = q * 8 + e;
    bbf01[j] = (k < 16) ? f2bf(lb2[20480 + k * 512 + uv]) : (short)0;
  } else if (i < 155648) {               // BBF10
    int j = i - 139264;
    int uvb = j >> 9, r = j & 511;
    int l = (r >> 3) & 63, e = r & 7;
    int q = l >> 4, col = l & 15;
    int uv = uvb * 16 + col, k = q * 8 + e;
    bbf10[j] = (k < 16) ? f2bf(lb2[28672 + k * 512 + uv]) : (short)0;
  }
}

// ---- pre-pass 3: per-sample h, h2, x0, x1 --------------------------------
__global__ void k_samples(const float* __restrict__ feat, const float* __restrict__ ne,
                          const float* __restrict__ W0, const float* __restrict__ W1,
                          const float* __restrict__ lw1, const float* __restrict__ lb1,
                          const float* __restrict__ bw1, const float* __restrict__ bb1,
                          float* __restrict__ H, float* __restrict__ H2,
                          float* __restrict__ X0, float* __restrict__ X1) {
  int b = blockIdx.x;
  int t = threadIdx.x;               // 192 threads
  __shared__ float sne[128];
  __shared__ float sf[320];
  if (t < 128) sne[t] = ne[(size_t)b * 128 + t];
  for (int i = t; i < 320; i += 192) sf[i] = feat[(size_t)b * 320 + i];
  __syncthreads();
  if (t < 64) {
    float a = lb1[t];
    for (int k = 0; k < 128; ++k) a += sne[k] * lw1[k * 64 + t];
    H[(size_t)b * 64 + t] = a / (1.0f + expf(-a));
  } else if (t < 128) {
    int c = t - 64;
    float a = bb1[c];
    for (int k = 0; k < 128; ++k) a += sne[k] * bw1[k * 64 + c];
    H2[(size_t)b * 64 + c] = a / (1.0f + expf(-a));
  } else if (t < 144) {
    int v = t - 128;
    float a = 0.0f;
    for (int u = 0; u < 128; ++u) a += sf[u] * W0[u * 16 + v];
    X0[(size_t)b * 16 + v] = a * 0.08838834764831845f;  // 1/sqrt(128)
  } else {
    int idx = t - 144, v = idx / 3, j = idx % 3;        // idx < 48
    float a = 0.0f;
    for (int u = 0; u < 64; ++u) a += sf[128 + u * 3 + j] * W1[u * 16 + v];
    X1[(size_t)b * 48 + v * 3 + j] = a * 0.125f;        // 1/sqrt(64)
  }
}

// ---- main kernel ----------------------------------------------------------
// Phase A helper: 2 sample-group Q-planes, NBIAS bias MFMAs, depth-4 pipe.
// B frag (kk,i) at LW2F + ((NB16 + (kk>>1)*NS16 + uvb + i)*2 + (kk&1))*512
//                + lane*8   -- one contiguous 1KB wave burst.
template <int N, int NB16, int NS16, int NBIAS>
static __device__ __forceinline__ void mmA2(
    const short* __restrict__ LW2F, const short* __restrict__ BBF,
    const short* __restrict__ sQp, const short* __restrict__ sAbp,
    int uvb, int lane, f32x4 (&acc)[2][N]) {
  const int lane8 = lane * 8;
  auto bptr = [&](int kk, int i) -> const bf16x8* {
    return (const bf16x8*)(LW2F +
        ((size_t)(NB16 + (kk >> 1) * NS16 + uvb + i) * 2 + (kk & 1)) * 512 + lane8);
  };
  bf16x8 B[4][N];
#pragma unroll
  for (int d = 0; d < 4; ++d)
#pragma unroll
    for (int i = 0; i < N; ++i) B[d][i] = *bptr(d, i);
#pragma unroll
  for (int kk = 0; kk < 32; ++kk) {
    const int d = kk & 3;
    const bf16x8 A0 = *(const bf16x8*)(sQp + kk * 512 + lane8);
    const bf16x8 A1 = *(const bf16x8*)(sQp + 16384 + kk * 512 + lane8);
#pragma unroll
    for (int i = 0; i < N; ++i) {
      acc[0][i] = __builtin_amdgcn_mfma_f32_16x16x32_bf16(A0, B[d][i], acc[0][i], 0, 0, 0);
      acc[1][i] = __builtin_amdgcn_mfma_f32_16x16x32_bf16(A1, B[d][i], acc[1][i], 0, 0, 0);
    }
    if (kk + 4 < 32) {
#pragma unroll
      for (int i = 0; i < N; ++i) B[d][i] = *bptr(kk + 4, i);
    }
  }
#pragma unroll
  for (int kk = 0; kk < NBIAS; ++kk) {
    const bf16x8 Ab0 = *(const bf16x8*)(sAbp + kk * 512 + lane8);
    const bf16x8 Ab1 = *(const bf16x8*)(sAbp + NBIAS * 512 + kk * 512 + lane8);
#pragma unroll
    for (int i = 0; i < N; ++i) {
      const bf16x8 Bx = *(const bf16x8*)(BBF +
          (size_t)((uvb + i) * NBIAS + kk) * 512 + lane8);
      acc[0][i] = __builtin_amdgcn_mfma_f32_16x16x32_bf16(Ab0, Bx, acc[0][i], 0, 0, 0);
      acc[1][i] = __builtin_amdgcn_mfma_f32_16x16x32_bf16(Ab1, Bx, acc[1][i], 0, 0, 0);
    }
  }
}

// Phase B helper: NP Q-planes share each B load; depth-4 pipeline.
template <int NP, int N, int NB16, int NS16>
static __device__ __forceinline__ void mmBnp(
    const short* __restrict__ LW2F, const short* __restrict__ BBF,
    const short* __restrict__ sQp, const short* __restrict__ sA1p,
    int uvb, int lane, f32x4 (&acc)[NP][N]) {
  const int lane8 = lane * 8;
  auto bptr = [&](int kk, int i) -> const bf16x8* {
    return (const bf16x8*)(LW2F +
        ((size_t)(NB16 + (kk >> 1) * NS16 + uvb + i) * 2 + (kk & 1)) * 512 + lane8);
  };
  bf16x8 B[4][N];
#pragma unroll
  for (int d = 0; d < 4; ++d)
#pragma unroll
    for (int i = 0; i < N; ++i) B[d][i] = *bptr(d, i);
#pragma unroll
  for (int kk = 0; kk < 32; ++kk) {
    const int d = kk & 3;
    bf16x8 A[NP];
#pragma unroll
    for (int p = 0; p < NP; ++p)
      A[p] = *(const bf16x8*)(sQp + p * 16384 + kk * 512 + lane8);
#pragma unroll
    for (int i = 0; i < N; ++i)
#pragma unroll
      for (int p = 0; p < NP; ++p)
        acc[p][i] = __builtin_amdgcn_mfma_f32_16x16x32_bf16(A[p], B[d][i], acc[p][i], 0, 0, 0);
    if (kk + 4 < 32) {
#pragma unroll
      for (int i = 0; i < N; ++i) B[d][i] = *bptr(kk + 4, i);
    }
  }
  // bias: k < 16 only; same B row for all planes
#pragma unroll
  for (int i = 0; i < N; ++i) {
    const bf16x8 Bx = *(const bf16x8*)(BBF + (size_t)(uvb + i) * 512 + lane8);
#pragma unroll
    for (int p = 0; p < NP; ++p) {
      const bf16x8 Ap = *(const bf16x8*)(sA1p + p * 512 + lane8);
      acc[p][i] = __builtin_amdgcn_mfma_f32_16x16x32_bf16(Ap, Bx, acc[p][i], 0, 0, 0);
    }
  }
}

__global__ __launch_bounds__(512, 1) void k_main(
    const short* __restrict__ LW2F,
    const short* __restrict__ BBF00, const short* __restrict__ BBF11,
    const short* __restrict__ BBF01, const short* __restrict__ BBF10,
    const float* __restrict__ H, const float* __restrict__ H2,
    const float* __restrict__ X0, const float* __restrict__ X1,
    float* __restrict__ out) {
  constexpr float S00 = 0.0625f;                  // 1/16
  constexpr float S3 = 0.036084391824351614f;     // (1/sqrt(3))/16

  // blockIdx = slot + 8*seq, slot = (s&3) + 4*h  ->  XCD = slot:
  // XCDs 0..3 only read B-half 0, XCDs 4..7 only half 1 (L2-resident).
  int idx = blockIdx.x;
  int slot = idx & 7;
  int h = slot >> 2;
  int s = (slot & 3) + 4 * (idx >> 3);   // 0..127
  int b0 = s << 5;                        // 32 samples per tile
  int t = threadIdx.x;                    // 512 threads = 8 waves
  int lane = t & 63, wave = t >> 6;
  int col = lane & 15, q = lane >> 4;

  __shared__ float sH[32][66];
  __shared__ float sX0[32][17];
  __shared__ float sX1[32][51];
  __shared__ short sQ[4][32][4][16][8];   // [plane][kk][q][col][e]
  __shared__ short sAb[2][3][4][16][8];   // phase-A bias planes per group
  __shared__ short sA1[3][2][4][16][8];   // phase-B bias planes [j][g]

  for (int i = t; i < 2048; i += 512)
    sH[i >> 6][i & 63] = H[(size_t)(b0 + (i >> 6)) * 64 + (i & 63)];
  sX0[t >> 4][t & 15] = X0[(size_t)(b0 + (t >> 4)) * 16 + (t & 15)];
  for (int i = t; i < 1536; i += 512)
    sX1[i / 48][i % 48] = X1[(size_t)(b0 + i / 48) * 48 + (i % 48)];
  __syncthreads();

  // ===== build phase-A Q planes (g=0,1), sAb, sA1 =========================
  for (int i = t; i < 16384; i += 512) {
    int p = i >> 13, rem = i & 8191;
    int kk = rem >> 8, qq = (rem >> 6) & 3, cc = (rem >> 2) & 15, e2 = (rem & 3) << 1;
    int k = kk * 32 + qq * 8 + e2;
    int w = k >> 6, c = k & 63;
    float xw = sX0[p * 16 + cc][w];
    unsigned lo = (unsigned short)f2bf(sH[p * 16 + cc][c] * xw);
    unsigned hi = (unsigned short)f2bf(sH[p * 16 + cc][c + 1] * xw);
    *(unsigned*)&sQ[p][kk][qq][cc][e2] = lo | (hi << 16);
  }
  for (int i = t; i < 3072; i += 512) {   // sAb
    int g = (i >= 1536), rem = i - (g ? 1536 : 0);
    int kk = rem >> 9, r2 = rem & 511;
    int qq = r2 >> 7, cc = (r2 >> 3) & 15, e = r2 & 7;
    int k = kk * 32 + qq * 8 + e;
    float v = 0.0f;
    if (k < 64) v = H2[(size_t)(b0 + g * 16 + cc) * 64 + k];
    else if (k < 80) v = sX0[g * 16 + cc][k - 64];
    else if (k == 80) v = 1.0f;
    sAb[g][kk][qq][cc][e] = f2bf(v);
  }
  for (int i = t; i < 3072; i += 512) {   // sA1 (all 3 j)
    int j = i >> 10, rem = i & 1023;
    int g = rem >> 9, r2 = rem & 511;
    int qq = r2 >> 7, cc = (r2 >> 3) & 15, e = r2 & 7;
    int k = qq * 8 + e;
    sA1[j][g][qq][cc][e] = (k < 16) ? f2bf(sX1[g * 16 + cc][k * 3 + j]) : (short)0;
  }
  __syncthreads();

  // ===== phase A: path00 (uv-half 512, wave owns 64) ======================
  {
    int uvb = h * 32 + wave * 4;
    f32x4 acc[2][4] = {};
    mmA2<4, 0, 64, 3>(LW2F, BBF00, &sQ[0][0][0][0][0], &sAb[0][0][0][0][0],
                      uvb, lane, acc);
#pragma unroll
    for (int g = 0; g < 2; ++g)
#pragma unroll
      for (int i = 0; i < 4; ++i)
#pragma unroll
        for (int ii = 0; ii < 4; ++ii) {
          size_t ob = (size_t)(b0 + g * 16 + q * 4 + ii) * 6400;
          int uv = (uvb + i) * 16 + col;
          out[ob + (uv >> 5) * 80 + (uv & 31)] = acc[g][i][ii] * S00;
        }
  }
  // path11 (uv-half 128, wave owns 16)
  {
    int uvb = h * 8 + wave;
    f32x4 acc[2][1] = {};
    mmA2<1, 1024, 16, 3>(LW2F, BBF11, &sQ[0][0][0][0][0], &sAb[0][0][0][0][0],
                         uvb, lane, acc);
#pragma unroll
    for (int g = 0; g < 2; ++g)
#pragma unroll
      for (int ii = 0; ii < 4; ++ii) {
        size_t ob = (size_t)(b0 + g * 16 + q * 4 + ii) * 6400;
        int uv = uvb * 16 + col;
        float val = acc[g][0][ii] * S3;
        int u = uv >> 4, v = uv & 15;
        float* p = out + ob + (size_t)(32 + 3 * u) * 80 + (32 + 3 * v);
        p[0] = val;   p[1] = 0.f;   p[2] = 0.f;
        p[80] = 0.f;  p[81] = val;  p[82] = 0.f;
        p[160] = 0.f; p[161] = 0.f; p[162] = val;
      }
  }

  // ===== phase B pass 1: planes (j,g) = (0,0),(0,1),(1,0),(1,1) ===========
  __syncthreads();
  for (int i = t; i < 32768; i += 512) {
    int p = i >> 13, rem = i & 8191;
    int j = p >> 1, g = p & 1;
    int kk = rem >> 8, qq = (rem >> 6) & 3, cc = (rem >> 2) & 15, e2 = (rem & 3) << 1;
    int k = kk * 32 + qq * 8 + e2;
    int w = k >> 6, c = k & 63;
    float xw = sX1[g * 16 + cc][w * 3 + j];
    unsigned lo = (unsigned short)f2bf(sH[g * 16 + cc][c] * xw);
    unsigned hi = (unsigned short)f2bf(sH[g * 16 + cc][c + 1] * xw);
    *(unsigned*)&sQ[p][kk][qq][cc][e2] = lo | (hi << 16);
  }
  __syncthreads();
  {
    int uvb = h * 16 + wave * 2;
    {
      f32x4 acc[4][2] = {};
      mmBnp<4, 2, 1280, 32>(LW2F, BBF01, &sQ[0][0][0][0][0],
                            &sA1[0][0][0][0][0], uvb, lane, acc);
#pragma unroll
      for (int p = 0; p < 4; ++p)
#pragma unroll
        for (int i = 0; i < 2; ++i)
#pragma unroll
          for (int ii = 0; ii < 4; ++ii) {
            int j = p >> 1, g = p & 1;
            size_t ob = (size_t)(b0 + g * 16 + q * 4 + ii) * 6400;
            int uv = (uvb + i) * 16 + col;
            out[ob + (uv >> 4) * 80 + 32 + 3 * (uv & 15) + j] = acc[p][i][ii] * S3;
          }
    }
    {
      f32x4 acc[4][2] = {};
      mmBnp<4, 2, 1792, 32>(LW2F, BBF10, &sQ[0][0][0][0][0],
                            &sA1[0][0][0][0][0], uvb, lane, acc);
#pragma unroll
      for (int p = 0; p < 4; ++p)
#pragma unroll
        for (int i = 0; i < 2; ++i)
#pragma unroll
          for (int ii = 0; ii < 4; ++ii) {
            int j = p >> 1, g = p & 1;
            size_t ob = (size_t)(b0 + g * 16 + q * 4 + ii) * 6400;
            int uv = (uvb + i) * 16 + col;
            out[ob + (size_t)(32 + 3 * (uv >> 5) + j) * 80 + (uv & 31)] = acc[p][i][ii] * S3;
          }
    }
  }

  // ===== phase B pass 2: planes g = 0,1 at j = 2 ==========================
  __syncthreads();
  for (int i = t; i < 16384; i += 512) {
    int g = i >> 13, rem = i & 8191;
    int kk = rem >> 8, qq = (rem >> 6) & 3, cc = (rem >> 2) & 15, e2 = (rem & 3) << 1;
    int k = kk * 32 + qq * 8 + e2;
    int w = k >> 6, c = k & 63;
    float xw = sX1[g * 16 + cc][w * 3 + 2];
    unsigned lo = (unsigned short)f2bf(sH[g * 16 + cc][c] * xw);
    unsigned hi = (unsigned short)f2bf(sH[g * 16 + cc][c + 1] * xw);
    *(unsigned*)&sQ[g][kk][qq][cc][e2] = lo | (hi << 16);
  }
  __syncthreads();
  {
    int uvb = h * 16 + wave * 2;
    {
      f32x4 acc[2][2] = {};
      mmBnp<2, 2, 1280, 32>(LW2F, BBF01, &sQ[0][0][0][0][0],
                            &sA1[2][0][0][0][0], uvb, lane, acc);
#pragma unroll
      for (int g = 0; g < 2; ++g)
#pragma unroll
        for (int i = 0; i < 2; ++i)
#pragma unroll
          for (int ii = 0; ii < 4; ++ii) {
            size_t ob = (size_t)(b0 + g * 16 + q * 4 + ii) * 6400;
            int uv = (uvb + i) * 16 + col;
            out[ob + (uv >> 4) * 80 + 32 + 3 * (uv & 15) + 2] = acc[g][i][ii] * S3;
          }
    }
    {
      f32x4 acc[2][2] = {};
      mmBnp<2, 2, 1792, 32>(LW2F, BBF10, &sQ[0][0][0][0][0],
                            &sA1[2][0][0][0][0], uvb, lane, acc);
#pragma unroll
      for (int g = 0; g < 2; ++g)
#pragma unroll
        for (int i = 0; i < 2; ++i)
#pragma unroll
          for (int ii = 0; ii < 4; ++ii) {
            size_t ob = (size_t)(b0 + g * 16 + q * 4 + ii) * 6400;
            int uv = (uvb + i) * 16 + col;
            out[ob + (size_t)(32 + 3 * (uv >> 5) + 2) * 80 + (uv & 31)] = acc[g][i][ii] * S3;
          }
    }
  }
}

// ---------------------------------------------------------------------------
extern "C" void kernel_launch(void* const* d_in, const int* in_sizes, int n_in,
                              void* d_out, int out_size, void* d_ws, size_t ws_size,
                              hipStream_t stream) {
  const float* feat = (const float*)d_in[0];
  const float* ne   = (const float*)d_in[1];
  const float* W0   = (const float*)d_in[2];
  const float* W1   = (const float*)d_in[3];
  const float* lw1  = (const float*)d_in[4];
  const float* lb1  = (const float*)d_in[5];
  const float* lw2  = (const float*)d_in[6];
  const float* lb2  = (const float*)d_in[7];
  const float* bw1  = (const float*)d_in[8];
  const float* bb1  = (const float*)d_in[9];
  const float* bw2  = (const float*)d_in[10];
  const float* bb2  = (const float*)d_in[11];

  char* ws = (char*)d_ws;
  short* LW2F = (short*)ws; ws += (size_t)36864 * 64 * 2;   // 4.72 MB
  short* BBF00 = (short*)ws; ws += (size_t)98304 * 2;
  short* BBF11 = (short*)ws; ws += (size_t)24576 * 2;
  short* BBF01 = (short*)ws; ws += (size_t)16384 * 2;
  short* BBF10 = (short*)ws; ws += (size_t)16384 * 2;
  float* H  = (float*)ws;   ws += (size_t)4096 * 64 * 4;
  float* H2 = (float*)ws;   ws += (size_t)4096 * 64 * 4;
  float* X0 = (float*)ws;   ws += (size_t)4096 * 16 * 4;
  float* X1 = (float*)ws;   ws += (size_t)4096 * 48 * 4;
  (void)ws_size; (void)in_sizes; (void)n_in; (void)out_size;

  hipLaunchKernelGGL(k_transpose, dim3(576), dim3(256), 0, stream, lw2, LW2F);
  hipLaunchKernelGGL(k_bias, dim3(608), dim3(256), 0, stream, bw2, lb2, bb2,
                     BBF00, BBF11, BBF01, BBF10);
  hipLaunchKernelGGL(k_samples, dim3(4096), dim3(192), 0, stream,
                     feat, ne, W0, W1, lw1, lb1, bw1, bb1, H, H2, X0, X1);
  hipLaunchKernelGGL(k_main, dim3(256), dim3(512), 0, stream,
                     LW2F, BBF00, BBF11, BBF01, BBF10, H, H2, X0, X1, (float*)d_out);
}